// Round 5
// baseline (4329.491 us; speedup 1.0000x reference)
//
#include <hip/hip_runtime.h>
#include <hip/hip_fp16.h>

#define D 128
#define NCHUNK 8      // feature chunks == XCD count; 16 feats (32 B fp16) per chunk
#define N_ITER 20

// ---------------- mask dtype detection ----------------
__global__ void k_detect(const unsigned char* __restrict__ m, int nbytes, int* flag) {
    __shared__ int s;
    if (threadIdx.x == 0) s = 0;
    __syncthreads();
    int c = 0;
    for (int i = threadIdx.x; i < nbytes; i += 256)
        if ((i & 3) && m[i]) c++;
    atomicAdd(&s, c);
    __syncthreads();
    if (threadIdx.x == 0) *flag = (s > 0) ? 1 : 0;
}

__global__ void k_mask(const void* __restrict__ mraw, const int* __restrict__ flag,
                       unsigned char* __restrict__ m8, int n) {
    int i = blockIdx.x * 256 + threadIdx.x;
    if (i >= n) return;
    unsigned char v;
    if (*flag) {
        v = ((const unsigned char*)mraw)[i] != 0;
    } else {
        v = ((const int*)mraw)[i] != 0;
    }
    m8[i] = v;
}

// ---------------- degree counting ----------------
__global__ void k_deg(const int* __restrict__ row, const int* __restrict__ col, int E,
                      const unsigned char* __restrict__ m8,
                      int* __restrict__ deg, int* __restrict__ rdeg) {
    int e = blockIdx.x * 256 + threadIdx.x;
    if (e >= E) return;
    atomicAdd(&deg[col[e]], 1);
    int r = row[e];
    if (!m8[r]) atomicAdd(&rdeg[r], 1);
}

__global__ void k_dis(const int* __restrict__ deg, float* __restrict__ dis, int n) {
    int i = blockIdx.x * 256 + threadIdx.x;
    if (i >= n) return;
    int d = deg[i];
    dis[i] = (d > 0) ? rsqrtf((float)d) : 0.f;
}

// ---------------- exclusive scan of rdeg -> row_off ----------------
__global__ void k_scan1(const int* __restrict__ rdeg, int* __restrict__ csum, int n) {
    __shared__ int sh[256];
    int base = blockIdx.x * 2048;
    int t = threadIdx.x;
    int s = 0;
    for (int j = 0; j < 8; j++) {
        int i = base + t * 8 + j;
        if (i < n) s += rdeg[i];
    }
    sh[t] = s;
    __syncthreads();
    for (int o = 128; o > 0; o >>= 1) {
        if (t < o) sh[t] += sh[t + o];
        __syncthreads();
    }
    if (t == 0) csum[blockIdx.x] = sh[0];
}

__global__ void k_scan2(int* __restrict__ csum, int nch, int* __restrict__ row_off, int n) {
    if (threadIdx.x == 0) {
        int acc = 0;
        for (int i = 0; i < nch; i++) { int v = csum[i]; csum[i] = acc; acc += v; }
        row_off[n] = acc;
    }
}

__global__ void k_scan3(const int* __restrict__ rdeg, const int* __restrict__ csum,
                        int* __restrict__ row_off, int n) {
    __shared__ int sh[256];
    int base = blockIdx.x * 2048;
    int t = threadIdx.x;
    int loc[8];
    int s = 0;
    for (int j = 0; j < 8; j++) {
        int i = base + t * 8 + j;
        int v = (i < n) ? rdeg[i] : 0;
        loc[j] = s;
        s += v;
    }
    sh[t] = s;
    __syncthreads();
    for (int o = 1; o < 256; o <<= 1) {
        int v = (t >= o) ? sh[t - o] : 0;
        __syncthreads();
        sh[t] += v;
        __syncthreads();
    }
    int toff = csum[blockIdx.x] + ((t > 0) ? sh[t - 1] : 0);
    for (int j = 0; j < 8; j++) {
        int i = base + t * 8 + j;
        if (i < n) row_off[i] = toff + loc[j];
    }
}

// ---------------- scatter (filtered) edges into CSR: col only ----------------
__global__ void k_scatter(const int* __restrict__ row, const int* __restrict__ col, int E,
                          const unsigned char* __restrict__ m8,
                          const int* __restrict__ row_off, int* __restrict__ cursor,
                          int* __restrict__ col_s) {
    int e = blockIdx.x * 256 + threadIdx.x;
    if (e >= E) return;
    int r = row[e];
    if (m8[r]) return;
    int p = row_off[r] + atomicAdd(&cursor[r], 1);
    col_s[p] = col[e];
}

// ---------------- compact unmasked rows ----------------
__global__ void k_compact(const unsigned char* __restrict__ m8, int n,
                          int* __restrict__ rows_c, int* __restrict__ cnt) {
    int i = blockIdx.x * 256 + threadIdx.x;
    if (i >= n) return;
    if (!m8[i]) {
        int p = atomicAdd(cnt, 1);
        rows_c[p] = i;
    }
}

// ---------------- init: chunk-major u0 = mask ? dis*x : 0; masked rows of d_out = x --------
// u layout (half2 units): u[chunk*N*8 + node*8 + f], chunk in [0,8), f in [0,8)
__global__ void k_init(const float* __restrict__ x, const unsigned char* __restrict__ m8,
                       const float* __restrict__ dis,
                       __half2* __restrict__ uA, __half2* __restrict__ uB,
                       float* __restrict__ out, int N) {
    int tid = blockIdx.x * 256 + threadIdx.x;   // one thread per (node, half2 pair)
    if (tid >= N * 64) return;
    int node = tid >> 6;
    int q = tid & 63;            // q-th half2 of the row
    int chunk = q >> 3, f = q & 7;
    __half2 u;
    if (m8[node]) {
        float2 v = ((const float2*)x)[tid];
        ((float2*)out)[tid] = v;                 // masked rows of d_out = x exactly
        float d = dis[node];
        u = __floats2half2_rn(d * v.x, d * v.y);
    } else {
        u = __floats2half2_rn(0.f, 0.f);
    }
    size_t p = (size_t)chunk * N * 8 + (size_t)node * 8 + f;
    uA[p] = u;
    uB[p] = u;
}

// ---------------- propagation: XCD-chunked ----------------
// chunk = blockIdx % 8 -> XCD (round-robin dispatch), src chunk (3.2 MB) stays L2-resident.
// 16 waves/block; one wave per unmasked row; lane = 8*sub + f: 8 edges in flight, 8 half2 each.
// u_new[r] = dis[r]^2 * sum_e u[col_e]; final: out[r] = dis[r] * sum_e u[col_e] (fp32).
template <bool FINAL>
__global__ __launch_bounds__(1024) void k_prop(const __half2* __restrict__ src,
                                               void* __restrict__ dst,
                                               const int* __restrict__ rows_c,
                                               const int* __restrict__ cnt_p,
                                               const int* __restrict__ row_off,
                                               const int* __restrict__ col_s,
                                               const float* __restrict__ dis, int N) {
    int chunk = blockIdx.x & 7;
    int wid = (blockIdx.x >> 3) * 16 + (threadIdx.x >> 6);
    int lane = threadIdx.x & 63;
    if (wid >= *cnt_p) return;
    int r = __builtin_amdgcn_readfirstlane(rows_c[wid]);
    int beg = __builtin_amdgcn_readfirstlane(row_off[r]);
    int end = __builtin_amdgcn_readfirstlane(row_off[r + 1]);

    int sub = lane >> 3;   // edge slot 0..7
    int f = lane & 7;      // half2 slot 0..7 within 16-feature chunk
    const __half2* cb = src + (size_t)chunk * N * 8 + f;  // node stride = 8 half2

    float ax = 0.f, ay = 0.f, bx = 0.f, by = 0.f;
    int e = beg;
    for (; e + 16 <= end; e += 16) {
        int c0 = __builtin_nontemporal_load(&col_s[e + sub]);
        int c1 = __builtin_nontemporal_load(&col_s[e + 8 + sub]);
        __half2 h0 = cb[(size_t)c0 * 8];
        __half2 h1 = cb[(size_t)c1 * 8];
        float2 v0 = __half22float2(h0);
        float2 v1 = __half22float2(h1);
        ax += v0.x; ay += v0.y;
        bx += v1.x; by += v1.y;
    }
    for (; e + 8 <= end; e += 8) {
        int c0 = __builtin_nontemporal_load(&col_s[e + sub]);
        float2 v0 = __half22float2(cb[(size_t)c0 * 8]);
        ax += v0.x; ay += v0.y;
    }
    if (e < end) {
        int idx = e + sub;
        if (idx < end) {
            int c0 = __builtin_nontemporal_load(&col_s[idx]);
            float2 v0 = __half22float2(cb[(size_t)c0 * 8]);
            ax += v0.x; ay += v0.y;
        }
    }
    ax += bx; ay += by;
    // reduce across the 8 edge slots (lane strides 8,16,32)
    ax += __shfl_xor(ax, 8, 64);  ay += __shfl_xor(ay, 8, 64);
    ax += __shfl_xor(ax, 16, 64); ay += __shfl_xor(ay, 16, 64);
    ax += __shfl_xor(ax, 32, 64); ay += __shfl_xor(ay, 32, 64);

    if (lane < 8) {
        float d = dis[r];
        if (FINAL) {
            // d_out row-major: float2 index r*64 + chunk*8 + f
            ((float2*)dst)[(size_t)r * 64 + chunk * 8 + f] = make_float2(d * ax, d * ay);
        } else {
            float s = d * d;
            __half2 hv = __floats2half2_rn(s * ax, s * ay);
            unsigned int bits;
            __builtin_memcpy(&bits, &hv, 4);
            unsigned int* p = (unsigned int*)&((__half2*)dst)[(size_t)chunk * N * 8 + (size_t)r * 8 + f];
            __builtin_nontemporal_store(bits, p);
        }
    }
}

extern "C" void kernel_launch(void* const* d_in, const int* in_sizes, int n_in,
                              void* d_out, int out_size, void* d_ws, size_t ws_size,
                              hipStream_t stream) {
    const float* x = (const float*)d_in[0];
    const int* ei = (const int*)d_in[1];
    const void* mraw = d_in[2];

    const int N = in_sizes[0] / D;     // 100000
    const int E = in_sizes[1] / 2;     // 3200000
    const int* row = ei;
    const int* col = ei + E;

    char* ws = (char*)d_ws;
    size_t off = 0;
    __half2* uA = (__half2*)(ws + off);     off += (size_t)N * D * 2;   // chunk-major half feats
    __half2* uB = (__half2*)(ws + off);     off += (size_t)N * D * 2;
    int* col_s = (int*)(ws + off);          off += (size_t)E * 4;       // CSR cols (filtered)
    int* row_off = (int*)(ws + off);        off += (size_t)(N + 1) * 4;
    int* zblock = (int*)(ws + off);         off += (size_t)(3 * N + 1) * 4; // deg|rdeg|cursor|cnt
    int* deg = zblock;
    int* rdeg = zblock + N;
    int* cursor = zblock + 2 * N;
    int* cnt = zblock + 3 * N;
    float* dis = (float*)(ws + off);        off += (size_t)N * 4;
    int* rows_c = (int*)(ws + off);         off += (size_t)N * 4;
    unsigned char* m8 = (unsigned char*)(ws + off); off += (size_t)N;
    off = (off + 255) & ~(size_t)255;
    int* csum = (int*)(ws + off);           off += 256 * 4;
    int* flag = (int*)(ws + off);           off += 4;

    (void)hipMemsetAsync(zblock, 0, (size_t)(3 * N + 1) * 4, stream);

    k_detect<<<1, 256, 0, stream>>>((const unsigned char*)mraw, N, flag);
    k_mask<<<(N + 255) / 256, 256, 0, stream>>>(mraw, flag, m8, N);
    k_deg<<<(E + 255) / 256, 256, 0, stream>>>(row, col, E, m8, deg, rdeg);
    k_dis<<<(N + 255) / 256, 256, 0, stream>>>(deg, dis, N);

    int nch = (N + 2047) / 2048;
    k_scan1<<<nch, 256, 0, stream>>>(rdeg, csum, N);
    k_scan2<<<1, 64, 0, stream>>>(csum, nch, row_off, N);
    k_scan3<<<nch, 256, 0, stream>>>(rdeg, csum, row_off, N);

    k_scatter<<<(E + 255) / 256, 256, 0, stream>>>(row, col, E, m8, row_off, cursor, col_s);
    k_compact<<<(N + 255) / 256, 256, 0, stream>>>(m8, N, rows_c, cnt);

    k_init<<<(N * 64 + 255) / 256, 256, 0, stream>>>(x, m8, dis, uA, uB, (float*)d_out, N);

    // 19 half iterations ping-pong, then final fp32 iteration into d_out.
    // grid: 8 chunks x ceil(N/16) row-groups; blockIdx%8 -> chunk -> XCD (round-robin).
    int blocks = 8 * ((N + 15) / 16);
    __half2* src = uA;
    __half2* dst = uB;
    for (int it = 0; it < N_ITER - 1; it++) {
        k_prop<false><<<blocks, 1024, 0, stream>>>(src, dst, rows_c, cnt, row_off, col_s, dis, N);
        __half2* t = src; src = dst; dst = t;
    }
    k_prop<true><<<blocks, 1024, 0, stream>>>(src, d_out, rows_c, cnt, row_off, col_s, dis, N);
}

// Round 6
// 1667.950 us; speedup vs baseline: 2.5957x; 2.5957x over previous
//
#include <hip/hip_runtime.h>
#include <hip/hip_fp16.h>

#define D 128
#define N_ITER 20

// ---------------- mask dtype detection ----------------
__global__ void k_detect(const unsigned char* __restrict__ m, int nbytes, int* flag) {
    __shared__ int s;
    if (threadIdx.x == 0) s = 0;
    __syncthreads();
    int c = 0;
    for (int i = threadIdx.x; i < nbytes; i += 256)
        if ((i & 3) && m[i]) c++;
    atomicAdd(&s, c);
    __syncthreads();
    if (threadIdx.x == 0) *flag = (s > 0) ? 1 : 0;
}

__global__ void k_mask(const void* __restrict__ mraw, const int* __restrict__ flag,
                       unsigned char* __restrict__ m8, int n) {
    int i = blockIdx.x * 256 + threadIdx.x;
    if (i >= n) return;
    unsigned char v;
    if (*flag) {
        v = ((const unsigned char*)mraw)[i] != 0;
    } else {
        v = ((const int*)mraw)[i] != 0;
    }
    m8[i] = v;
}

// ---------------- degree counting ----------------
__global__ void k_deg(const int* __restrict__ row, const int* __restrict__ col, int E,
                      const unsigned char* __restrict__ m8,
                      int* __restrict__ deg, int* __restrict__ rdeg) {
    int e = blockIdx.x * 256 + threadIdx.x;
    if (e >= E) return;
    atomicAdd(&deg[col[e]], 1);
    int r = row[e];
    if (!m8[r]) atomicAdd(&rdeg[r], 1);
}

__global__ void k_dis(const int* __restrict__ deg, float* __restrict__ dis, int n) {
    int i = blockIdx.x * 256 + threadIdx.x;
    if (i >= n) return;
    int d = deg[i];
    dis[i] = (d > 0) ? rsqrtf((float)d) : 0.f;
}

// ---------------- exclusive scan of rdeg -> row_off ----------------
__global__ void k_scan1(const int* __restrict__ rdeg, int* __restrict__ csum, int n) {
    __shared__ int sh[256];
    int base = blockIdx.x * 2048;
    int t = threadIdx.x;
    int s = 0;
    for (int j = 0; j < 8; j++) {
        int i = base + t * 8 + j;
        if (i < n) s += rdeg[i];
    }
    sh[t] = s;
    __syncthreads();
    for (int o = 128; o > 0; o >>= 1) {
        if (t < o) sh[t] += sh[t + o];
        __syncthreads();
    }
    if (t == 0) csum[blockIdx.x] = sh[0];
}

__global__ void k_scan2(int* __restrict__ csum, int nch, int* __restrict__ row_off, int n) {
    if (threadIdx.x == 0) {
        int acc = 0;
        for (int i = 0; i < nch; i++) { int v = csum[i]; csum[i] = acc; acc += v; }
        row_off[n] = acc;
    }
}

__global__ void k_scan3(const int* __restrict__ rdeg, const int* __restrict__ csum,
                        int* __restrict__ row_off, int n) {
    __shared__ int sh[256];
    int base = blockIdx.x * 2048;
    int t = threadIdx.x;
    int loc[8];
    int s = 0;
    for (int j = 0; j < 8; j++) {
        int i = base + t * 8 + j;
        int v = (i < n) ? rdeg[i] : 0;
        loc[j] = s;
        s += v;
    }
    sh[t] = s;
    __syncthreads();
    for (int o = 1; o < 256; o <<= 1) {
        int v = (t >= o) ? sh[t - o] : 0;
        __syncthreads();
        sh[t] += v;
        __syncthreads();
    }
    int toff = csum[blockIdx.x] + ((t > 0) ? sh[t - 1] : 0);
    for (int j = 0; j < 8; j++) {
        int i = base + t * 8 + j;
        if (i < n) row_off[i] = toff + loc[j];
    }
}

// ---------------- scatter (filtered) edges into CSR: col only ----------------
__global__ void k_scatter(const int* __restrict__ row, const int* __restrict__ col, int E,
                          const unsigned char* __restrict__ m8,
                          const int* __restrict__ row_off, int* __restrict__ cursor,
                          int* __restrict__ col_s) {
    int e = blockIdx.x * 256 + threadIdx.x;
    if (e >= E) return;
    int r = row[e];
    if (m8[r]) return;
    int p = row_off[r] + atomicAdd(&cursor[r], 1);
    col_s[p] = col[e];
}

// ---------------- compact unmasked rows ----------------
__global__ void k_compact(const unsigned char* __restrict__ m8, int n,
                          int* __restrict__ rows_c, int* __restrict__ cnt) {
    int i = blockIdx.x * 256 + threadIdx.x;
    if (i >= n) return;
    if (!m8[i]) {
        int p = atomicAdd(cnt, 1);
        rows_c[p] = i;
    }
}

// ---------------- init: row-major u0 = mask ? dis*x : 0 (both buffers); d_out masked = x ----
__global__ void k_init(const float* __restrict__ x, const unsigned char* __restrict__ m8,
                       const float* __restrict__ dis,
                       __half2* __restrict__ uA, __half2* __restrict__ uB,
                       float* __restrict__ out, int nvec) {
    int i = blockIdx.x * 256 + threadIdx.x;  // float4 index, 32 per node
    if (i >= nvec) return;
    int node = i >> 5;
    __half2 h0, h1;
    if (m8[node]) {
        float4 v = ((const float4*)x)[i];
        ((float4*)out)[i] = v;               // masked rows of d_out = x exactly
        float d = dis[node];
        h0 = __floats2half2_rn(d * v.x, d * v.y);
        h1 = __floats2half2_rn(d * v.z, d * v.w);
    } else {
        h0 = __floats2half2_rn(0.f, 0.f);
        h1 = h0;
    }
    uA[i * 2] = h0; uA[i * 2 + 1] = h1;
    uB[i * 2] = h0; uB[i * 2 + 1] = h1;
}

// ---------------- propagation: one wave per unmasked row ----------------
// lane = 32*s + f : s = edge slot (0/1), f = half4 slot within the 256B row.
// 8-deep unroll -> 16 edges / 4KB in flight per wave.
// u_new[r] = dis[r]^2 * sum_e u[col_e]; final: out[r] = dis[r] * sum (fp32 to d_out).
template <bool FINAL>
__global__ __launch_bounds__(256) void k_prop(const uint2* __restrict__ src,
                                              void* __restrict__ dst,
                                              const int* __restrict__ rows_c,
                                              const int* __restrict__ cnt_p,
                                              const int* __restrict__ row_off,
                                              const int* __restrict__ col_s,
                                              const float* __restrict__ dis) {
    int wid = (blockIdx.x * 256 + threadIdx.x) >> 6;
    int lane = threadIdx.x & 63;
    if (wid >= *cnt_p) return;
    int r = __builtin_amdgcn_readfirstlane(rows_c[wid]);
    int beg = __builtin_amdgcn_readfirstlane(row_off[r]);
    int end = __builtin_amdgcn_readfirstlane(row_off[r + 1]);

    int s = lane >> 5;     // edge slot 0..1
    int f = lane & 31;     // uint2 (half4) slot, row stride 32 uint2
    const uint2* cb = src + f;

    float a0 = 0.f, a1 = 0.f, a2 = 0.f, a3 = 0.f;
    float b0 = 0.f, b1 = 0.f, b2 = 0.f, b3 = 0.f;

    int e = beg;
    for (; e + 16 <= end; e += 16) {
        int c[8];
#pragma unroll
        for (int j = 0; j < 8; j++) c[j] = col_s[e + 2 * j + s];
        uint2 g[8];
#pragma unroll
        for (int j = 0; j < 8; j++) g[j] = cb[(size_t)c[j] * 32];
#pragma unroll
        for (int j = 0; j < 8; j++) {
            __half2 hlo, hhi;
            __builtin_memcpy(&hlo, &g[j].x, 4);
            __builtin_memcpy(&hhi, &g[j].y, 4);
            float2 vlo = __half22float2(hlo);
            float2 vhi = __half22float2(hhi);
            if (j & 1) { b0 += vlo.x; b1 += vlo.y; b2 += vhi.x; b3 += vhi.y; }
            else       { a0 += vlo.x; a1 += vlo.y; a2 += vhi.x; a3 += vhi.y; }
        }
    }
    for (; e + 2 <= end; e += 2) {
        int c = col_s[e + s];
        uint2 g = cb[(size_t)c * 32];
        __half2 hlo, hhi;
        __builtin_memcpy(&hlo, &g.x, 4);
        __builtin_memcpy(&hhi, &g.y, 4);
        float2 vlo = __half22float2(hlo);
        float2 vhi = __half22float2(hhi);
        a0 += vlo.x; a1 += vlo.y; a2 += vhi.x; a3 += vhi.y;
    }
    if (e < end && s == 0) {   // odd tail edge, handled by slot 0 only
        int c = col_s[e];
        uint2 g = cb[(size_t)c * 32];
        __half2 hlo, hhi;
        __builtin_memcpy(&hlo, &g.x, 4);
        __builtin_memcpy(&hhi, &g.y, 4);
        float2 vlo = __half22float2(hlo);
        float2 vhi = __half22float2(hhi);
        a0 += vlo.x; a1 += vlo.y; a2 += vhi.x; a3 += vhi.y;
    }
    a0 += b0; a1 += b1; a2 += b2; a3 += b3;
    // combine the two edge slots (lane xor 32)
    a0 += __shfl_xor(a0, 32, 64);
    a1 += __shfl_xor(a1, 32, 64);
    a2 += __shfl_xor(a2, 32, 64);
    a3 += __shfl_xor(a3, 32, 64);

    if (lane < 32) {
        float d = dis[r];
        if (FINAL) {
            ((float4*)dst)[(size_t)r * 32 + f] = make_float4(d * a0, d * a1, d * a2, d * a3);
        } else {
            float ss = d * d;
            __half2 h0 = __floats2half2_rn(ss * a0, ss * a1);
            __half2 h1 = __floats2half2_rn(ss * a2, ss * a3);
            uint2 o;
            __builtin_memcpy(&o.x, &h0, 4);
            __builtin_memcpy(&o.y, &h1, 4);
            ((uint2*)dst)[(size_t)r * 32 + f] = o;
        }
    }
}

extern "C" void kernel_launch(void* const* d_in, const int* in_sizes, int n_in,
                              void* d_out, int out_size, void* d_ws, size_t ws_size,
                              hipStream_t stream) {
    const float* x = (const float*)d_in[0];
    const int* ei = (const int*)d_in[1];
    const void* mraw = d_in[2];

    const int N = in_sizes[0] / D;     // 100000
    const int E = in_sizes[1] / 2;     // 3200000
    const int* row = ei;
    const int* col = ei + E;

    char* ws = (char*)d_ws;
    size_t off = 0;
    __half2* uA = (__half2*)(ws + off);     off += (size_t)N * D * 2;   // row-major half feats
    __half2* uB = (__half2*)(ws + off);     off += (size_t)N * D * 2;
    int* col_s = (int*)(ws + off);          off += (size_t)E * 4;       // CSR cols (filtered)
    int* row_off = (int*)(ws + off);        off += (size_t)(N + 1) * 4;
    int* zblock = (int*)(ws + off);         off += (size_t)(3 * N + 1) * 4; // deg|rdeg|cursor|cnt
    int* deg = zblock;
    int* rdeg = zblock + N;
    int* cursor = zblock + 2 * N;
    int* cnt = zblock + 3 * N;
    float* dis = (float*)(ws + off);        off += (size_t)N * 4;
    int* rows_c = (int*)(ws + off);         off += (size_t)N * 4;
    unsigned char* m8 = (unsigned char*)(ws + off); off += (size_t)N;
    off = (off + 255) & ~(size_t)255;
    int* csum = (int*)(ws + off);           off += 256 * 4;
    int* flag = (int*)(ws + off);           off += 4;

    (void)hipMemsetAsync(zblock, 0, (size_t)(3 * N + 1) * 4, stream);

    k_detect<<<1, 256, 0, stream>>>((const unsigned char*)mraw, N, flag);
    k_mask<<<(N + 255) / 256, 256, 0, stream>>>(mraw, flag, m8, N);
    k_deg<<<(E + 255) / 256, 256, 0, stream>>>(row, col, E, m8, deg, rdeg);
    k_dis<<<(N + 255) / 256, 256, 0, stream>>>(deg, dis, N);

    int nch = (N + 2047) / 2048;
    k_scan1<<<nch, 256, 0, stream>>>(rdeg, csum, N);
    k_scan2<<<1, 64, 0, stream>>>(csum, nch, row_off, N);
    k_scan3<<<nch, 256, 0, stream>>>(rdeg, csum, row_off, N);

    k_scatter<<<(E + 255) / 256, 256, 0, stream>>>(row, col, E, m8, row_off, cursor, col_s);
    k_compact<<<(N + 255) / 256, 256, 0, stream>>>(m8, N, rows_c, cnt);

    int nvec = N * (D / 4);
    k_init<<<(nvec + 255) / 256, 256, 0, stream>>>(x, m8, dis, uA, uB, (float*)d_out, nvec);

    // 19 half iterations ping-pong, then final fp32 iteration into d_out
    uint2* src = (uint2*)uA;
    uint2* dst = (uint2*)uB;
    int blocks = (N + 3) / 4;  // 4 waves per block (upper bound on cnt)
    for (int it = 0; it < N_ITER - 1; it++) {
        k_prop<false><<<blocks, 256, 0, stream>>>(src, dst, rows_c, cnt, row_off, col_s, dis);
        uint2* t = src; src = dst; dst = t;
    }
    k_prop<true><<<blocks, 256, 0, stream>>>(src, d_out, rows_c, cnt, row_off, col_s, dis);
}